// Round 8
// baseline (4344.339 us; speedup 1.0000x reference)
//
#include <hip/hip_runtime.h>

// ---------------------------------------------------------------------------
// 2-layer LSTM (H=51) + Linear(51,1), B=1024, T=1024, fp32.
// Design (R8): SINGLE-BARRIER pipelined step. R7 counters (VGPR=60, no spill,
// yet 3.2 ms, VALUBusy 38%) proved the cost is the per-step critical path
// (3 barriers + LDS gate round-trips), not memory. Changes:
//   - Layer 2 runs ONE STEP BEHIND layer 1: iteration k computes L1(step k)
//     and L2(step k-1). Both read only pre-barrier state -> 1 barrier/iter.
//   - Unit-major mapping tid = u*16 + gate*4 + chunk: the 4 gates of unit u
//     live in one 16-lane in-wave group -> c/h update via shuffles
//     (redundant on 16 lanes), NO gate LDS round-trip.
//   - h1/h2 in ping-pong LDS buffers (2x64 floats each); broadcast b128 reads.
//   - y = W_lin.h2 on 16 spare lanes, two steps deferred (off critical path).
//   - split-4 weights: 24 f2 = 48 VGPRs/lane, "+v"-pinned (R7-proven no-spill).
//   - waves_per_eu(1,4): 128-reg allocator target (R7-proven safe vs spill).
// ---------------------------------------------------------------------------

#define H    51
#define NG   204
#define TLEN 1024
#define NTHR 832      // 13 waves: 816 dot lanes (51 groups of 16) + 16 spares
#define NBLK 1024

typedef __attribute__((ext_vector_type(2))) float f2;
typedef __attribute__((ext_vector_type(4))) float f4;

__device__ __forceinline__ float frcp(float x) { return __builtin_amdgcn_rcpf(x); }
__device__ __forceinline__ float ftanh(float x) {
    return 1.0f - 2.0f * frcp(__expf(2.0f * x) + 1.0f);
}

#define F2LO(V) (f2{(V).x, (V).y})
#define F2HI(V) (f2{(V).z, (V).w})

__global__
__attribute__((amdgpu_flat_work_group_size(NTHR, NTHR), amdgpu_waves_per_eu(1, 4)))
void lstm2_kernel(const float* __restrict__ input,
                  const float* __restrict__ W_ih1, const float* __restrict__ W_hh1,
                  const float* __restrict__ b_ih1, const float* __restrict__ b_hh1,
                  const float* __restrict__ W_ih2, const float* __restrict__ W_hh2,
                  const float* __restrict__ b_ih2, const float* __restrict__ b_hh2,
                  const float* __restrict__ W_lin, const float* __restrict__ b_lin,
                  float* __restrict__ out)
{
    const int tid  = threadIdx.x;
    const int b    = blockIdx.x;
    const int u    = tid >> 4;           // unit 0..50 (51 = spare group)
    const int gidx = (tid >> 2) & 3;     // gate: 0=i 1=f 2=g 3=o
    const int chl  = tid & 3;            // K-chunk
    const int cs   = chl * 16;           // chunk start in padded-64 h
    const bool dl  = (u < H);            // dot lane
    const int r    = dl ? (gidx * H + u) : 0;      // weight row

    __shared__ __align__(16) float h1buf[2][64];   // ping-pong, zero-padded
    __shared__ __align__(16) float h2buf[2][64];

    if (tid < 128) h1buf[tid >> 6][tid & 63] = 0.0f;
    else if (tid < 256) h2buf[(tid - 128) >> 6][tid & 63] = 0.0f;

    // per-lane weight chunk (zero-padded past element 50), pinned in VGPRs
    f2 w1[8], wi2[8], wh2[8];
#pragma unroll
    for (int j = 0; j < 8; ++j) {
        const int e0 = cs + 2 * j, e1 = e0 + 1;
        const bool v0 = dl && (e0 < H), v1 = dl && (e1 < H);
        w1[j]  = f2{v0 ? W_hh1[r * H + e0] : 0.0f, v1 ? W_hh1[r * H + e1] : 0.0f};
        wi2[j] = f2{v0 ? W_ih2[r * H + e0] : 0.0f, v1 ? W_ih2[r * H + e1] : 0.0f};
        wh2[j] = f2{v0 ? W_hh2[r * H + e0] : 0.0f, v1 ? W_hh2[r * H + e1] : 0.0f};
    }
#pragma unroll
    for (int j = 0; j < 8; ++j) {
        asm volatile("" : "+v"(w1[j]), "+v"(wi2[j]), "+v"(wh2[j]));
    }

    const float wx  = dl ? W_ih1[r] : 0.0f;
    const float bb1 = dl ? (b_ih1[r] + b_hh1[r]) : 0.0f;
    const float bb2 = dl ? (b_ih2[r] + b_hh2[r]) : 0.0f;

    // gate act: gidx==2 -> tanh else sigmoid; act(x)=am*rcp(1+exp(sm*x))+bm
    const float sm = (gidx == 2) ? -2.0f : -1.0f;
    const float am = (gidx == 2) ?  2.0f :  1.0f;
    const float bm = (gidx == 2) ? -1.0f :  0.0f;

    // spare lanes (tid 816..831): y-dot chunk of W_lin (padded)
    const int sj = tid - 816;
    f4 wl4 = f4{0.0f, 0.0f, 0.0f, 0.0f};
    if (tid >= 816) {
        const int e = sj * 4;
        wl4 = f4{(e + 0 < H) ? W_lin[e + 0] : 0.0f,
                 (e + 1 < H) ? W_lin[e + 1] : 0.0f,
                 (e + 2 < H) ? W_lin[e + 2] : 0.0f,
                 (e + 3 < H) ? W_lin[e + 3] : 0.0f};
    }
    const float blin = b_lin[0];

    // in-wave gather sources (constant across iterations)
    const int gl = (tid & 63) & 48;      // 16-lane group base within wave
    const int s0 = gl + chl, s1 = gl + 4 + chl, s2 = gl + 8 + chl, s3 = gl + 12 + chl;
    const bool wlane = dl && ((tid & 15) == 0);    // one writer per group

    float c1 = 0.0f, c2 = 0.0f;
    const float* xrow = input + (size_t)b * TLEN;
    float*       orow = out   + (size_t)b * TLEN;

    __syncthreads();                     // zeros visible

    for (int k = 0; k <= TLEN; ++k) {
        const int rb = (k + 1) & 1;      // buffer written at iter k-1
        const int wb = k & 1;
        const float x = xrow[k < TLEN ? k : TLEN - 1];

        // ---- spares: y(k-2) from h2buf[rb] (stable this iteration) ----
        if (tid >= 816 && k >= 2) {
            const f4 hv = *(const f4*)&h2buf[rb][sj * 4];
            float yp = hv.x * wl4.x + hv.y * wl4.y + hv.z * wl4.z + hv.w * wl4.w;
            yp += __shfl_xor(yp, 1);  yp += __shfl_xor(yp, 2);
            yp += __shfl_xor(yp, 4);  yp += __shfl_xor(yp, 8);
            if (tid == 816) orow[k - 2] = yp + blin;
        }

        // ---- broadcast-read h chunks ----
        const f4* h1r = (const f4*)&h1buf[rb][cs];
        const f4* h2r = (const f4*)&h2buf[rb][cs];
        const f4 A0 = h1r[0], A1 = h1r[1], A2 = h1r[2], A3 = h1r[3];
        const f4 B0 = h2r[0], B1 = h2r[1], B2 = h2r[2], B3 = h2r[3];

        // ---- L1 gates (step k): dot over own chunk, quad-reduce ----
        f2 pa = w1[0] * F2LO(A0), pb = w1[1] * F2HI(A0);
        pa = w1[2] * F2LO(A1) + pa;  pb = w1[3] * F2HI(A1) + pb;
        pa = w1[4] * F2LO(A2) + pa;  pb = w1[5] * F2HI(A2) + pb;
        pa = w1[6] * F2LO(A3) + pa;  pb = w1[7] * F2HI(A3) + pb;
        float pre1 = (pa.x + pb.x) + (pa.y + pb.y);
        pre1 += __shfl_xor(pre1, 1);
        pre1 += __shfl_xor(pre1, 2);
        pre1 += bb1 + wx * x;                       // added AFTER reduce
        const float ga1 = am * frcp(1.0f + __expf(sm * pre1)) + bm;

        // in-wave gather i,f,g,o for unit u; redundant c1 on 16 lanes
        const float i1 = __shfl(ga1, s0);
        const float f1 = __shfl(ga1, s1);
        const float g1 = __shfl(ga1, s2);
        const float o1 = __shfl(ga1, s3);
        c1 = f1 * c1 + i1 * g1;
        const float h1n = o1 * ftanh(c1);
        if (wlane) h1buf[wb][u] = h1n;

        // ---- L2 gates (step k-1): uses h1(k-1) [=A regs] and h2(k-2) ----
        f2 qa = wi2[0] * F2LO(A0), qb = wi2[1] * F2HI(A0);
        qa = wi2[2] * F2LO(A1) + qa;  qb = wi2[3] * F2HI(A1) + qb;
        qa = wi2[4] * F2LO(A2) + qa;  qb = wi2[5] * F2HI(A2) + qb;
        qa = wi2[6] * F2LO(A3) + qa;  qb = wi2[7] * F2HI(A3) + qb;
        qa = wh2[0] * F2LO(B0) + qa;  qb = wh2[1] * F2HI(B0) + qb;
        qa = wh2[2] * F2LO(B1) + qa;  qb = wh2[3] * F2HI(B1) + qb;
        qa = wh2[4] * F2LO(B2) + qa;  qb = wh2[5] * F2HI(B2) + qb;
        qa = wh2[6] * F2LO(B3) + qa;  qb = wh2[7] * F2HI(B3) + qb;
        float pre2 = (qa.x + qb.x) + (qa.y + qb.y);
        pre2 += __shfl_xor(pre2, 1);
        pre2 += __shfl_xor(pre2, 2);
        pre2 += bb2;
        const float ga2 = am * frcp(1.0f + __expf(sm * pre2)) + bm;

        const float i2 = __shfl(ga2, s0);
        const float fg2 = __shfl(ga2, s1);
        const float g2 = __shfl(ga2, s2);
        const float o2 = __shfl(ga2, s3);
        if (k != 0) {                                // L2 step k-1 exists
            c2 = fg2 * c2 + i2 * g2;
            const float h2n = o2 * ftanh(c2);
            if (wlane) h2buf[wb][u] = h2n;
        }

        __syncthreads();                             // THE one barrier
    }

    // epilogue: y(T-1) from h2buf[T&1] (written at iter T, post-barrier)
    if (tid >= 816) {
        const f4 hv = *(const f4*)&h2buf[TLEN & 1][sj * 4];
        float yp = hv.x * wl4.x + hv.y * wl4.y + hv.z * wl4.z + hv.w * wl4.w;
        yp += __shfl_xor(yp, 1);  yp += __shfl_xor(yp, 2);
        yp += __shfl_xor(yp, 4);  yp += __shfl_xor(yp, 8);
        if (tid == 816) orow[TLEN - 1] = yp + blin;
    }
}

extern "C" void kernel_launch(void* const* d_in, const int* in_sizes, int n_in,
                              void* d_out, int out_size, void* d_ws, size_t ws_size,
                              hipStream_t stream)
{
    const float* input = (const float*)d_in[0];
    const float* W_ih1 = (const float*)d_in[1];
    const float* W_hh1 = (const float*)d_in[2];
    const float* b_ih1 = (const float*)d_in[3];
    const float* b_hh1 = (const float*)d_in[4];
    const float* W_ih2 = (const float*)d_in[5];
    const float* W_hh2 = (const float*)d_in[6];
    const float* b_ih2 = (const float*)d_in[7];
    const float* b_hh2 = (const float*)d_in[8];
    const float* W_lin = (const float*)d_in[9];
    const float* b_lin = (const float*)d_in[10];

    float* out = (float*)d_out;

    hipLaunchKernelGGL(lstm2_kernel, dim3(NBLK), dim3(NTHR), 0, stream,
                       input, W_ih1, W_hh1, b_ih1, b_hh1,
                       W_ih2, W_hh2, b_ih2, b_hh2, W_lin, b_lin,
                       out);
}

// Round 9
// 2523.987 us; speedup vs baseline: 1.7212x; 1.7212x over previous
//
#include <hip/hip_runtime.h>

// ---------------------------------------------------------------------------
// 2-layer LSTM (H=51) + Linear(51,1), B=1024, T=1024, fp32.
// Design (R9): quad-local gates, DPP exchange, 2 blocks/CU.
//   - lane (a = tid>>3, c = tid&7) owns rows {a,51+a,102+a,153+a} x h[8c..8c+7]
//     -> weights 3 x 16 f2 = 96 VGPRs, "+v"-pinned.
//   - reduce: per gate, quad DPP xor1(0xB1)+xor2(0x4E) adds, then select own
//     gate (q=c&3) and ONE __shfl_xor(4). Every lane ends with its unit's
//     pre-act; c/h update fully in-quad via 2 DPP quad_perm moves. No gate
//     LDS round-trip at all (R8 had 12 LDS-shuffles/lane on the one LDS pipe).
//   - single barrier/step, L2 skewed one step behind L1 (R8-proven).
//   - 512 threads (8 waves), 1024 blocks; waves_per_eu(4,4) pins the VGPR
//     class at 128 -> 2 blocks/CU -> 2 batches/CU -> 2 generations (R7/R8 had
//     4). Cross-block barrier interleave hides per-step latency.
//   - y = W_lin.h2: 16 spare lanes at tid 416 (16-ALIGNED for xor4/xor8),
//     one step deferred, off the critical path. W_lin staged in LDS (0 VGPRs).
// ---------------------------------------------------------------------------

#define H    51
#define TLEN 1024
#define NTHR 512
#define NBLK 1024

typedef __attribute__((ext_vector_type(2))) float f2;
typedef __attribute__((ext_vector_type(4))) float f4;

__device__ __forceinline__ float frcp(float x) { return __builtin_amdgcn_rcpf(x); }

// quad_perm DPP: out lane i = in lane sel_i. 0xB1 = [1,0,3,2] (xor1),
// 0x4E = [2,3,0,1] (xor2 / swap02_13). VALU pipe, no LDS.
#define DPP_XADD(X, CTRL) ((X) + __int_as_float(__builtin_amdgcn_update_dpp( \
                              0, __float_as_int(X), CTRL, 0xF, 0xF, true)))
#define DPP_GET(X, CTRL)  (__int_as_float(__builtin_amdgcn_update_dpp(       \
                              0, __float_as_int(X), CTRL, 0xF, 0xF, true)))

#define F2LO(V) (f2{(V).x, (V).y})
#define F2HI(V) (f2{(V).z, (V).w})

__global__
__attribute__((amdgpu_flat_work_group_size(NTHR, NTHR), amdgpu_waves_per_eu(4, 4)))
void lstm2_kernel(const float* __restrict__ input,
                  const float* __restrict__ W_ih1, const float* __restrict__ W_hh1,
                  const float* __restrict__ b_ih1, const float* __restrict__ b_hh1,
                  const float* __restrict__ W_ih2, const float* __restrict__ W_hh2,
                  const float* __restrict__ b_ih2, const float* __restrict__ b_hh2,
                  const float* __restrict__ W_lin, const float* __restrict__ b_lin,
                  float* __restrict__ out)
{
    const int tid = threadIdx.x;
    const int b   = blockIdx.x;
    const int a   = tid >> 3;        // unit 0..63 (a<51 active)
    const int c   = tid & 7;         // k-chunk 0..7 (8 floats)
    const int q   = c & 3;           // this lane's gate: 0=i 1=f 2=g 3=o
    const bool ul = (a < H);

    __shared__ __align__(16) float h1buf[2][64];   // ping-pong, zero-padded
    __shared__ __align__(16) float h2buf[2][64];
    __shared__ __align__(16) float sh_wl[64];      // W_lin, zero-padded

    if (tid < 128)      h1buf[tid >> 6][tid & 63] = 0.0f;
    else if (tid < 256) h2buf[(tid >> 6) & 1][tid & 63] = 0.0f;
    else if (tid < 320) sh_wl[tid - 256] = (tid - 256 < H) ? W_lin[tid - 256] : 0.0f;

    // per-lane weights: rows g*51+a, elements [8c, 8c+8), zero-padded
    f2 w1[16], wi2[16], wh2[16];
#pragma unroll
    for (int g = 0; g < 4; ++g) {
#pragma unroll
        for (int j = 0; j < 4; ++j) {
            const int e0 = c * 8 + 2 * j, e1 = e0 + 1;
            const int r  = g * H + a;
            const bool v0 = ul && (e0 < H), v1 = ul && (e1 < H);
            w1 [g*4+j] = f2{v0 ? W_hh1[r*H+e0] : 0.f, v1 ? W_hh1[r*H+e1] : 0.f};
            wi2[g*4+j] = f2{v0 ? W_ih2[r*H+e0] : 0.f, v1 ? W_ih2[r*H+e1] : 0.f};
            wh2[g*4+j] = f2{v0 ? W_hh2[r*H+e0] : 0.f, v1 ? W_hh2[r*H+e1] : 0.f};
        }
    }
#pragma unroll
    for (int g = 0; g < 4; ++g)
        asm volatile("" : "+v"(w1[g*4+0]),  "+v"(w1[g*4+1]),  "+v"(w1[g*4+2]),  "+v"(w1[g*4+3]),
                          "+v"(wi2[g*4+0]), "+v"(wi2[g*4+1]), "+v"(wi2[g*4+2]), "+v"(wi2[g*4+3]),
                          "+v"(wh2[g*4+0]), "+v"(wh2[g*4+1]), "+v"(wh2[g*4+2]), "+v"(wh2[g*4+3]));

    const int rq = q * H + a;                      // this lane's gate row
    const float wx  = ul ? W_ih1[rq] : 0.f;
    const float bb1 = ul ? (b_ih1[rq] + b_hh1[rq]) : 0.f;
    const float bb2 = ul ? (b_ih2[rq] + b_hh2[rq]) : 0.f;
    const float sm  = (q == 2) ? -2.0f : -1.0f;    // tanh gate = scaled sigmoid
    const float bm  = (q == 2) ? -1.0f :  0.0f;    // act = sg + bm*(1-sg)

    const int  sj    = tid - 416;                  // y lanes: 416..431 (16-aligned)
    const bool ylane = ((unsigned)sj < 16u);
    const float blin = b_lin[0];

    float c1 = 0.0f, c2 = 0.0f;
    const float* xrow = input + (size_t)b * TLEN;
    float*       orow = out   + (size_t)b * TLEN;

    __syncthreads();                               // zeros + sh_wl visible

    for (int k = 0; k <= TLEN; ++k) {
        const int rb = (k + 1) & 1;                // holds h1(k-1), h2(k-2)
        const int wb = k & 1;
        const float x = xrow[k < TLEN ? k : TLEN - 1];

        // ---- deferred y(k-2) on spare lanes (off critical path) ----
        if (ylane && k >= 2) {
            const f4 hv = *(const f4*)&h2buf[rb][sj * 4];
            const f4 wl = *(const f4*)&sh_wl[sj * 4];
            float yp = hv.x*wl.x + hv.y*wl.y + hv.z*wl.z + hv.w*wl.w;
            yp = DPP_XADD(yp, 0xB1);  yp = DPP_XADD(yp, 0x4E);
            yp += __shfl_xor(yp, 4);  yp += __shfl_xor(yp, 8);
            if (sj == 0) orow[k - 2] = yp + blin;
        }

        // ---- stage h1(k-1) chunk, L1 dots, full reduce -> sel1 ----
        const f4* h1v = (const f4*)&h1buf[rb][c * 8];
        const f4 A0 = h1v[0], A1 = h1v[1];
        float sel1;
        {
            float t0, t1, t2, t3;
            { f2 acc = w1[0]*F2LO(A0);  acc = w1[1]*F2HI(A0)+acc;
              acc = w1[2]*F2LO(A1)+acc; acc = w1[3]*F2HI(A1)+acc; t0 = acc.x+acc.y; }
            { f2 acc = w1[4]*F2LO(A0);  acc = w1[5]*F2HI(A0)+acc;
              acc = w1[6]*F2LO(A1)+acc; acc = w1[7]*F2HI(A1)+acc; t1 = acc.x+acc.y; }
            { f2 acc = w1[8]*F2LO(A0);  acc = w1[9]*F2HI(A0)+acc;
              acc = w1[10]*F2LO(A1)+acc; acc = w1[11]*F2HI(A1)+acc; t2 = acc.x+acc.y; }
            { f2 acc = w1[12]*F2LO(A0); acc = w1[13]*F2HI(A0)+acc;
              acc = w1[14]*F2LO(A1)+acc; acc = w1[15]*F2HI(A1)+acc; t3 = acc.x+acc.y; }
            t0 = DPP_XADD(t0, 0xB1); t0 = DPP_XADD(t0, 0x4E);
            t1 = DPP_XADD(t1, 0xB1); t1 = DPP_XADD(t1, 0x4E);
            t2 = DPP_XADD(t2, 0xB1); t2 = DPP_XADD(t2, 0x4E);
            t3 = DPP_XADD(t3, 0xB1); t3 = DPP_XADD(t3, 0x4E);
            float s = (q & 2) ? ((q & 1) ? t3 : t2) : ((q & 1) ? t1 : t0);
            s += __shfl_xor(s, 4);                 // combine the two half-chunks
            sel1 = s;
        }

        // ---- stage h2(k-2) chunk, L2 dots (wi2.h1 + wh2.h2) -> sel2 ----
        const f4* h2v = (const f4*)&h2buf[rb][c * 8];
        const f4 B0 = h2v[0], B1 = h2v[1];
        float sel2;
        {
            float t0, t1, t2, t3;
            { f2 acc = wi2[0]*F2LO(A0);  acc = wi2[1]*F2HI(A0)+acc;
              acc = wi2[2]*F2LO(A1)+acc; acc = wi2[3]*F2HI(A1)+acc;
              acc = wh2[0]*F2LO(B0)+acc; acc = wh2[1]*F2HI(B0)+acc;
              acc = wh2[2]*F2LO(B1)+acc; acc = wh2[3]*F2HI(B1)+acc; t0 = acc.x+acc.y; }
            { f2 acc = wi2[4]*F2LO(A0);  acc = wi2[5]*F2HI(A0)+acc;
              acc = wi2[6]*F2LO(A1)+acc; acc = wi2[7]*F2HI(A1)+acc;
              acc = wh2[4]*F2LO(B0)+acc; acc = wh2[5]*F2HI(B0)+acc;
              acc = wh2[6]*F2LO(B1)+acc; acc = wh2[7]*F2HI(B1)+acc; t1 = acc.x+acc.y; }
            { f2 acc = wi2[8]*F2LO(A0);  acc = wi2[9]*F2HI(A0)+acc;
              acc = wi2[10]*F2LO(A1)+acc; acc = wi2[11]*F2HI(A1)+acc;
              acc = wh2[8]*F2LO(B0)+acc;  acc = wh2[9]*F2HI(B0)+acc;
              acc = wh2[10]*F2LO(B1)+acc; acc = wh2[11]*F2HI(B1)+acc; t2 = acc.x+acc.y; }
            { f2 acc = wi2[12]*F2LO(A0); acc = wi2[13]*F2HI(A0)+acc;
              acc = wi2[14]*F2LO(A1)+acc; acc = wi2[15]*F2HI(A1)+acc;
              acc = wh2[12]*F2LO(B0)+acc; acc = wh2[13]*F2HI(B0)+acc;
              acc = wh2[14]*F2LO(B1)+acc; acc = wh2[15]*F2HI(B1)+acc; t3 = acc.x+acc.y; }
            t0 = DPP_XADD(t0, 0xB1); t0 = DPP_XADD(t0, 0x4E);
            t1 = DPP_XADD(t1, 0xB1); t1 = DPP_XADD(t1, 0x4E);
            t2 = DPP_XADD(t2, 0xB1); t2 = DPP_XADD(t2, 0x4E);
            t3 = DPP_XADD(t3, 0xB1); t3 = DPP_XADD(t3, 0x4E);
            float s = (q & 2) ? ((q & 1) ? t3 : t2) : ((q & 1) ? t1 : t0);
            s += __shfl_xor(s, 4);
            sel2 = s;
        }

        // ---- L1 act + in-quad exchange + c1/h1 update (step k) ----
        {
            const float pre  = sel1 + bb1 + wx * x;
            const float sg   = frcp(1.0f + __expf(sm * pre));
            const float act  = sg + bm * (1.0f - sg);      // sigmoid or tanh
            const float bx   = DPP_GET(act, 0x4E);         // partner gate (i<->g, f<->o)
            const float p    = act * bx;                   // even lanes: i*g
            const float fown = (q == 1) ? act : bx;        // odd lanes hold f
            const float send = (q & 1) ? fown : p;
            const float w    = DPP_GET(send, 0xB1);
            const float fv   = (q & 1) ? fown : w;
            const float pv   = (q & 1) ? w : p;
            c1 = fv * c1 + pv;
            const float th = 1.0f - 2.0f * frcp(__expf(2.0f * c1) + 1.0f);
            if (ul && c == 1) h1buf[wb][a] = bx * th;      // q==1 lane: bx = o
        }

        // ---- L2 act + exchange + c2/h2 update (step k-1) ----
        {
            const float pre  = sel2 + bb2;
            const float sg   = frcp(1.0f + __expf(sm * pre));
            const float act  = sg + bm * (1.0f - sg);
            const float bx   = DPP_GET(act, 0x4E);
            const float p    = act * bx;
            const float fown = (q == 1) ? act : bx;
            const float send = (q & 1) ? fown : p;
            const float w    = DPP_GET(send, 0xB1);
            const float fv   = (q & 1) ? fown : w;
            const float pv   = (q & 1) ? w : p;
            if (k != 0) {                                  // step k-1 exists
                c2 = fv * c2 + pv;
                const float th = 1.0f - 2.0f * frcp(__expf(2.0f * c2) + 1.0f);
                if (ul && c == 1) h2buf[wb][a] = bx * th;
            }
        }

        __syncthreads();                                   // the one barrier
    }

    // epilogue: y(T-1) from h2buf[TLEN & 1] (written at iter k=TLEN)
    if (ylane) {
        const f4 hv = *(const f4*)&h2buf[TLEN & 1][sj * 4];
        const f4 wl = *(const f4*)&sh_wl[sj * 4];
        float yp = hv.x*wl.x + hv.y*wl.y + hv.z*wl.z + hv.w*wl.w;
        yp = DPP_XADD(yp, 0xB1);  yp = DPP_XADD(yp, 0x4E);
        yp += __shfl_xor(yp, 4);  yp += __shfl_xor(yp, 8);
        if (sj == 0) orow[TLEN - 1] = yp + blin;
    }
}

extern "C" void kernel_launch(void* const* d_in, const int* in_sizes, int n_in,
                              void* d_out, int out_size, void* d_ws, size_t ws_size,
                              hipStream_t stream)
{
    const float* input = (const float*)d_in[0];
    const float* W_ih1 = (const float*)d_in[1];
    const float* W_hh1 = (const float*)d_in[2];
    const float* b_ih1 = (const float*)d_in[3];
    const float* b_hh1 = (const float*)d_in[4];
    const float* W_ih2 = (const float*)d_in[5];
    const float* W_hh2 = (const float*)d_in[6];
    const float* b_ih2 = (const float*)d_in[7];
    const float* b_hh2 = (const float*)d_in[8];
    const float* W_lin = (const float*)d_in[9];
    const float* b_lin = (const float*)d_in[10];

    float* out = (float*)d_out;

    hipLaunchKernelGGL(lstm2_kernel, dim3(NBLK), dim3(NTHR), 0, stream,
                       input, W_ih1, W_hh1, b_ih1, b_hh1,
                       W_ih2, W_hh2, b_ih2, b_hh2, W_lin, b_lin,
                       out);
}

// Round 10
// 2243.392 us; speedup vs baseline: 1.9365x; 1.1251x over previous
//
#include <hip/hip_runtime.h>

// ---------------------------------------------------------------------------
// 2-layer LSTM (H=51) + Linear(51,1), B=1024, T=1024, fp32.
// Design (R10 = R9 skeleton, instruction-count attack):
//   R9 counters: VALUBusy 83% (issue-bound) but VGPR_Count=64 < 96 weight
//   floats -> weights lived in AGPRs; every dot op paid v_accvgpr_read
//   copies (~+96 instr/step = the 3x bloat over static count).
//   - dots: inline-asm v_pk_fma_f32 / v_pk_mul_f32. Guarantees packed math
//     AND forces weights into VGPRs at each use (no AGPR copy tax).
//   - quad reduce: select-exchange butterfly (12 instr) instead of 4x full
//     DPP-reduce + select tree. Lane q = c&3 ends owning gate q.
//   - c/h exchange in-quad: bx = dpp_xor2(act) (partner gate), i*g via
//     dpp broadcast lane0, f via dpp broadcast lane1. Writer lane: q==3 (o).
//   - branchless k==0 guard for L2 (mask multiply; writes exact 0 at k=0).
//   - single barrier/step, L2 one step behind L1, ping-pong h buffers,
//     y on 16 spare lanes (tid 416..431) one step deferred  [all R9-proven].
// ---------------------------------------------------------------------------

#define H    51
#define TLEN 1024
#define NTHR 512
#define NBLK 1024

typedef __attribute__((ext_vector_type(2))) float f2;
typedef __attribute__((ext_vector_type(4))) float f4;

__device__ __forceinline__ float frcp(float x) { return __builtin_amdgcn_rcpf(x); }

// packed fp32: D = A*B (+D). 64-bit VGPR-pair operands; "v" forces VGPRs.
#define PKMUL(D, A, B) asm("v_pk_mul_f32 %0, %1, %2"     : "=v"(D) : "v"(A), "v"(B))
#define PKFMA(D, A, B) asm("v_pk_fma_f32 %0, %1, %2, %0" : "+v"(D) : "v"(A), "v"(B))

// quad_perm DPP (VALU pipe): 0xB1=[1,0,3,2] xor1, 0x4E=[2,3,0,1] xor2,
// 0x00=bcast lane0, 0x55=bcast lane1.
#define DPP_GET(X, CTRL)  (__int_as_float(__builtin_amdgcn_update_dpp(       \
                              0, __float_as_int(X), CTRL, 0xF, 0xF, true)))
#define DPP_XADD(X, CTRL) ((X) + DPP_GET(X, CTRL))

__global__
__attribute__((amdgpu_flat_work_group_size(NTHR, NTHR), amdgpu_waves_per_eu(4, 4)))
void lstm2_kernel(const float* __restrict__ input,
                  const float* __restrict__ W_ih1, const float* __restrict__ W_hh1,
                  const float* __restrict__ b_ih1, const float* __restrict__ b_hh1,
                  const float* __restrict__ W_ih2, const float* __restrict__ W_hh2,
                  const float* __restrict__ b_ih2, const float* __restrict__ b_hh2,
                  const float* __restrict__ W_lin, const float* __restrict__ b_lin,
                  float* __restrict__ out)
{
    const int tid = threadIdx.x;
    const int b   = blockIdx.x;
    const int a   = tid >> 3;        // unit 0..63 (a<51 active)
    const int c   = tid & 7;         // k-chunk 0..7 (8 floats of h)
    const int q   = c & 3;           // after reduce, this lane owns gate q
    const bool ul = (a < H);

    __shared__ __align__(16) float h1buf[2][64];   // ping-pong, zero-padded
    __shared__ __align__(16) float h2buf[2][64];
    __shared__ __align__(16) float sh_wl[64];      // W_lin, zero-padded

    if (tid < 128)      h1buf[tid >> 6][tid & 63] = 0.0f;
    else if (tid < 256) h2buf[(tid >> 6) & 1][tid & 63] = 0.0f;
    else if (tid < 320) sh_wl[tid - 256] = (tid - 256 < H) ? W_lin[tid - 256] : 0.0f;

    // per-lane weights: rows g*51+a, elements [8c, 8c+8), zero-padded
    f2 w1[16], wi2[16], wh2[16];
#pragma unroll
    for (int g = 0; g < 4; ++g) {
#pragma unroll
        for (int j = 0; j < 4; ++j) {
            const int e0 = c * 8 + 2 * j, e1 = e0 + 1;
            const int r  = g * H + a;
            const bool v0 = ul && (e0 < H), v1 = ul && (e1 < H);
            w1 [g*4+j] = f2{v0 ? W_hh1[r*H+e0] : 0.f, v1 ? W_hh1[r*H+e1] : 0.f};
            wi2[g*4+j] = f2{v0 ? W_ih2[r*H+e0] : 0.f, v1 ? W_ih2[r*H+e1] : 0.f};
            wh2[g*4+j] = f2{v0 ? W_hh2[r*H+e0] : 0.f, v1 ? W_hh2[r*H+e1] : 0.f};
        }
    }

    const int rq = q * H + a;                      // this lane's own gate row
    const float wx  = ul ? W_ih1[rq] : 0.f;
    const float bb1 = ul ? (b_ih1[rq] + b_hh1[rq]) : 0.f;
    const float bb2 = ul ? (b_ih2[rq] + b_hh2[rq]) : 0.f;
    const float sm  = (q == 2) ? -2.0f : -1.0f;    // tanh gate as scaled sigmoid
    const float bm  = (q == 2) ? -1.0f :  0.0f;    // act = sg + bm*(1-sg)

    const int  sj    = tid - 416;                  // y lanes 416..431 (16-aligned)
    const bool ylane = ((unsigned)sj < 16u);
    const float blin = b_lin[0];

    float c1 = 0.0f, c2 = 0.0f;
    const float* xrow = input + (size_t)b * TLEN;
    float*       orow = out   + (size_t)b * TLEN;

    __syncthreads();                               // zeros + sh_wl visible

    for (int k = 0; k <= TLEN; ++k) {
        const int rb = (k + 1) & 1;                // holds h1(k-1), h2(k-2)
        const int wb = k & 1;
        const float x  = xrow[k < TLEN ? k : TLEN - 1];
        const float km = (k == 0) ? 0.0f : 1.0f;   // L2 step k-1 validity mask

        // ---- deferred y(k-2) on spare lanes (off critical path) ----
        if (ylane && k >= 2) {
            const f4 hv = *(const f4*)&h2buf[rb][sj * 4];
            const f4 wl = *(const f4*)&sh_wl[sj * 4];
            float yp = hv.x*wl.x + hv.y*wl.y + hv.z*wl.z + hv.w*wl.w;
            yp = DPP_XADD(yp, 0xB1);  yp = DPP_XADD(yp, 0x4E);
            yp += __shfl_xor(yp, 4);  yp += __shfl_xor(yp, 8);
            if (sj == 0) orow[k - 2] = yp + blin;
        }

        // ---- stage h chunks (ds_read_b128, broadcast within 8-lane sets) ----
        const f4* h1v = (const f4*)&h1buf[rb][c * 8];
        const f4* h2v = (const f4*)&h2buf[rb][c * 8];
        const f4 A0 = h1v[0], A1 = h1v[1];
        const f4 B0 = h2v[0], B1 = h2v[1];
        const f2 a0l = f2{A0.x, A0.y}, a0h = f2{A0.z, A0.w};
        const f2 a1l = f2{A1.x, A1.y}, a1h = f2{A1.z, A1.w};
        const f2 b0l = f2{B0.x, B0.y}, b0h = f2{B0.z, B0.w};
        const f2 b1l = f2{B1.x, B1.y}, b1h = f2{B1.z, B1.w};

        // ---- L1 per-gate partial dots (packed, forced) ----
        f2 p0, p1, p2, p3;
        PKMUL(p0, w1[0],  a0l); PKFMA(p0, w1[1],  a0h); PKFMA(p0, w1[2],  a1l); PKFMA(p0, w1[3],  a1h);
        PKMUL(p1, w1[4],  a0l); PKFMA(p1, w1[5],  a0h); PKFMA(p1, w1[6],  a1l); PKFMA(p1, w1[7],  a1h);
        PKMUL(p2, w1[8],  a0l); PKFMA(p2, w1[9],  a0h); PKFMA(p2, w1[10], a1l); PKFMA(p2, w1[11], a1h);
        PKMUL(p3, w1[12], a0l); PKFMA(p3, w1[13], a0h); PKFMA(p3, w1[14], a1l); PKFMA(p3, w1[15], a1h);
        float t0 = p0.x + p0.y, t1 = p1.x + p1.y, t2 = p2.x + p2.y, t3 = p3.x + p3.y;

        // ---- transpose-reduce: lane q ends with gate q (quad sum) ----
        float sel1;
        {
            const float s01 = (q & 1) ? t0 : t1, o01 = (q & 1) ? t1 : t0;
            const float s23 = (q & 1) ? t2 : t3, o23 = (q & 1) ? t3 : t2;
            const float aa = o01 + DPP_GET(s01, 0xB1);
            const float bb = o23 + DPP_GET(s23, 0xB1);
            const float yv = (q & 2) ? aa : bb, ov = (q & 2) ? bb : aa;
            float s = ov + DPP_GET(yv, 0x4E);
            s += __shfl_xor(s, 4);                 // combine half-chunks
            sel1 = s;
        }

        // ---- L2 per-gate partial dots: wi2.h1(k-1) + wh2.h2(k-2) ----
        PKMUL(p0, wi2[0],  a0l); PKFMA(p0, wi2[1],  a0h); PKFMA(p0, wi2[2],  a1l); PKFMA(p0, wi2[3],  a1h);
        PKFMA(p0, wh2[0],  b0l); PKFMA(p0, wh2[1],  b0h); PKFMA(p0, wh2[2],  b1l); PKFMA(p0, wh2[3],  b1h);
        PKMUL(p1, wi2[4],  a0l); PKFMA(p1, wi2[5],  a0h); PKFMA(p1, wi2[6],  a1l); PKFMA(p1, wi2[7],  a1h);
        PKFMA(p1, wh2[4],  b0l); PKFMA(p1, wh2[5],  b0h); PKFMA(p1, wh2[6],  b1l); PKFMA(p1, wh2[7],  b1h);
        PKMUL(p2, wi2[8],  a0l); PKFMA(p2, wi2[9],  a0h); PKFMA(p2, wi2[10], a1l); PKFMA(p2, wi2[11], a1h);
        PKFMA(p2, wh2[8],  b0l); PKFMA(p2, wh2[9],  b0h); PKFMA(p2, wh2[10], b1l); PKFMA(p2, wh2[11], b1h);
        PKMUL(p3, wi2[12], a0l); PKFMA(p3, wi2[13], a0h); PKFMA(p3, wi2[14], a1l); PKFMA(p3, wi2[15], a1h);
        PKFMA(p3, wh2[12], b0l); PKFMA(p3, wh2[13], b0h); PKFMA(p3, wh2[14], b1l); PKFMA(p3, wh2[15], b1h);
        t0 = p0.x + p0.y; t1 = p1.x + p1.y; t2 = p2.x + p2.y; t3 = p3.x + p3.y;

        float sel2;
        {
            const float s01 = (q & 1) ? t0 : t1, o01 = (q & 1) ? t1 : t0;
            const float s23 = (q & 1) ? t2 : t3, o23 = (q & 1) ? t3 : t2;
            const float aa = o01 + DPP_GET(s01, 0xB1);
            const float bb = o23 + DPP_GET(s23, 0xB1);
            const float yv = (q & 2) ? aa : bb, ov = (q & 2) ? bb : aa;
            float s = ov + DPP_GET(yv, 0x4E);
            s += __shfl_xor(s, 4);
            sel2 = s;
        }

        // ---- L1 act + in-quad exchange + c1/h1 update (step k) ----
        {
            const float pre = sel1 + bb1 + wx * x;
            const float sg  = frcp(1.0f + __expf(sm * pre));
            const float act = sg + bm * (1.0f - sg);       // lane q: gate q
            const float bx  = DPP_GET(act, 0x4E);          // partner (i<->g, f<->o)
            const float p   = act * bx;                    // lanes 0,2: i*g
            const float pv  = DPP_GET(p,   0x00);          // bcast i*g
            const float fv  = DPP_GET(act, 0x55);          // bcast f
            c1 = fv * c1 + pv;
            const float th = 1.0f - 2.0f * frcp(__expf(2.0f * c1) + 1.0f);
            if (ul && c == 3) h1buf[wb][a] = act * th;     // lane q==3: act = o
        }

        // ---- L2 act + exchange + c2/h2 update (step k-1; masked at k=0) ----
        {
            const float pre = sel2 + bb2;
            const float sg  = frcp(1.0f + __expf(sm * pre));
            const float act = sg + bm * (1.0f - sg);
            const float bx  = DPP_GET(act, 0x4E);
            const float p   = act * bx;
            const float pv  = DPP_GET(p,   0x00);
            const float fv  = DPP_GET(act, 0x55);
            c2 = fv * c2 + km * pv;                        // k=0: c2 stays 0
            const float th = 1.0f - 2.0f * frcp(__expf(2.0f * c2) + 1.0f);
            if (ul && c == 3) h2buf[wb][a] = act * th;     // k=0 writes exact 0
        }

        __syncthreads();                                   // the one barrier
    }

    // epilogue: y(T-1) from h2buf[TLEN & 1] (written at iter k=TLEN)
    if (ylane) {
        const f4 hv = *(const f4*)&h2buf[TLEN & 1][sj * 4];
        const f4 wl = *(const f4*)&sh_wl[sj * 4];
        float yp = hv.x*wl.x + hv.y*wl.y + hv.z*wl.z + hv.w*wl.w;
        yp = DPP_XADD(yp, 0xB1);  yp = DPP_XADD(yp, 0x4E);
        yp += __shfl_xor(yp, 4);  yp += __shfl_xor(yp, 8);
        if (sj == 0) orow[TLEN - 1] = yp + blin;
    }
}

extern "C" void kernel_launch(void* const* d_in, const int* in_sizes, int n_in,
                              void* d_out, int out_size, void* d_ws, size_t ws_size,
                              hipStream_t stream)
{
    const float* input = (const float*)d_in[0];
    const float* W_ih1 = (const float*)d_in[1];
    const float* W_hh1 = (const float*)d_in[2];
    const float* b_ih1 = (const float*)d_in[3];
    const float* b_hh1 = (const float*)d_in[4];
    const float* W_ih2 = (const float*)d_in[5];
    const float* W_hh2 = (const float*)d_in[6];
    const float* b_ih2 = (const float*)d_in[7];
    const float* b_hh2 = (const float*)d_in[8];
    const float* W_lin = (const float*)d_in[9];
    const float* b_lin = (const float*)d_in[10];

    float* out = (float*)d_out;

    hipLaunchKernelGGL(lstm2_kernel, dim3(NBLK), dim3(NTHR), 0, stream,
                       input, W_ih1, W_hh1, b_ih1, b_hh1,
                       W_ih2, W_hh2, b_ih2, b_hh2, W_lin, b_lin,
                       out);
}